// Round 10
// baseline (228.052 us; speedup 1.0000x reference)
//
#include <hip/hip_runtime.h>

#define BB 8
#define NN 8700
#define CC 256
#define QQ 300
#define HH 8
#define DD 32
#define HIDN 1024
#define NSPLIT 20
#define TSTR (NSPLIT * 64)
#define KSLACK 1536

typedef unsigned short u16;
typedef __attribute__((ext_vector_type(8))) short short8;
typedef __attribute__((ext_vector_type(4))) float f32x4;

#define MFMA16(a, b, c) __builtin_amdgcn_mfma_f32_16x16x32_bf16((a), (b), (c), 0, 0, 0)

__device__ __forceinline__ u16 f2bu(float f) {
    unsigned int u = __builtin_bit_cast(unsigned int, f);
    u += 0x7fffu + ((u >> 16) & 1u);   // round-to-nearest-even
    return (u16)(u >> 16);
}
__device__ __forceinline__ unsigned int cvtpk(float lo, float hi) {
    unsigned int r;
    asm("v_cvt_pk_bf16_f32 %0, %1, %2" : "=v"(r) : "v"(lo), "v"(hi));
    return r;
}
__device__ __forceinline__ void gload16(const u16* g, u16* l) {
    __builtin_amdgcn_global_load_lds(
        (const __attribute__((address_space(1))) void*)g,
        (__attribute__((address_space(3))) void*)l, 16, 0, 0);
}

// ---------------- tiled weight transpose: coalesced read + coalesced write ----------------
// dst element regions: WqT@0 WkT@64K WvT@128K WpT@192K W1T@256K W2T@512K
__global__ __launch_bounds__(256)
void wprep_t(const float* __restrict__ Wq, const float* __restrict__ Wk,
             const float* __restrict__ Wv, const float* __restrict__ Wp,
             const float* __restrict__ W1, const float* __restrict__ W2,
             u16* __restrict__ dst, float qscale)
{
    __shared__ u16 tl[64][66];
    int bid = blockIdx.x;
    const float* src; int K, N, tr, tc; size_t dof; float sc = 1.f;
    if (bid < 64) {
        int mat = bid >> 4, ti = bid & 15;
        src = (mat == 0) ? Wq : (mat == 1) ? Wk : (mat == 2) ? Wv : Wp;
        K = 256; N = 256; tr = ti >> 2; tc = ti & 3;
        dof = (size_t)mat * 65536;
        if (mat == 0) sc = qscale;
    } else if (bid < 128) {
        int ti = bid - 64; src = W1; K = 256; N = 1024; tr = ti >> 4; tc = ti & 15; dof = 262144;
    } else {
        int ti = bid - 128; src = W2; K = 1024; N = 256; tr = ti >> 2; tc = ti & 3; dof = 524288;
    }
    int tid = threadIdx.x;
    int jj = tid & 63;
    int i0 = tid >> 6;
#pragma unroll
    for (int ii = 0; ii < 16; ii++) {
        int kk = i0 * 16 + ii;
        float v = src[(size_t)(tr * 64 + kk) * N + tc * 64 + jj] * sc;
        tl[kk][jj] = f2bu(v);
    }
    __syncthreads();
#pragma unroll
    for (int ii = 0; ii < 16; ii++) {
        int nn = i0 * 16 + ii;
        dst[dof + (size_t)(tc * 64 + nn) * K + tr * 64 + jj] = tl[jj][nn];
    }
}

// ---------------- LN1 + context-token output ----------------
__global__ __launch_bounds__(256)
void ln1_k(const float* __restrict__ x, const float* __restrict__ w,
           const float* __restrict__ bv, const float* __restrict__ g1,
           u16* __restrict__ xn, float* __restrict__ out)
{
    int row = blockIdx.x * 4 + (threadIdx.x >> 6);
    int l = threadIdx.x & 63;
    size_t base = (size_t)row * CC + l * 4;
    float4 xv = *reinterpret_cast<const float4*>(x + base);
    float s  = xv.x + xv.y + xv.z + xv.w;
    float s2 = xv.x * xv.x + xv.y * xv.y + xv.z * xv.z + xv.w * xv.w;
#pragma unroll
    for (int m = 1; m < 64; m <<= 1) {
        s  += __shfl_xor(s,  m, 64);
        s2 += __shfl_xor(s2, m, 64);
    }
    float mean = s * (1.0f / CC);
    float rs = rsqrtf(s2 * (1.0f / CC) - mean * mean + 1e-5f);
    float4 wv = *reinterpret_cast<const float4*>(w  + l * 4);
    float4 bb = *reinterpret_cast<const float4*>(bv + l * 4);
    float n0 = (xv.x - mean) * rs * wv.x + bb.x;
    float n1 = (xv.y - mean) * rs * wv.y + bb.y;
    float n2 = (xv.z - mean) * rs * wv.z + bb.z;
    float n3 = (xv.w - mean) * rs * wv.w + bb.w;
    ushort4 u; u.x = f2bu(n0); u.y = f2bu(n1); u.z = f2bu(n2); u.w = f2bu(n3);
    *reinterpret_cast<ushort4*>(xn + base) = u;
    int n = row % NN;
    if (n >= QQ) {
        float4 gv = *reinterpret_cast<const float4*>(g1 + l * 4);
        float4 o;
        o.x = 2.0f * (xv.x + gv.x * n0);
        o.y = 2.0f * (xv.y + gv.y * n1);
        o.z = 2.0f * (xv.z + gv.z * n2);
        o.w = 2.0f * (xv.w + gv.w * n3);
        *reinterpret_cast<float4*>(out + base) = o;
    }
}

// ---------------- residual + LN2 for query tokens ----------------
__global__ __launch_bounds__(256)
void ln2_k(const float* __restrict__ x, const float* __restrict__ pd,
           const float* __restrict__ g1, const float* __restrict__ w,
           const float* __restrict__ bv, float* __restrict__ xqf, u16* __restrict__ xqb)
{
    int r = blockIdx.x * 4 + (threadIdx.x >> 6);
    int l = threadIdx.x & 63;
    int b = r / QQ, n = r - b * QQ;
    size_t xoff = ((size_t)b * NN + n) * CC + l * 4;
    size_t roff = (size_t)r * CC + l * 4;
    float4 xv = *reinterpret_cast<const float4*>(x + xoff);
    float4 pv = *reinterpret_cast<const float4*>(pd + roff);
    float4 gv = *reinterpret_cast<const float4*>(g1 + l * 4);
    float x0 = xv.x + gv.x * pv.x;
    float x1 = xv.y + gv.y * pv.y;
    float x2 = xv.z + gv.z * pv.z;
    float x3 = xv.w + gv.w * pv.w;
    float s  = x0 + x1 + x2 + x3;
    float s2 = x0 * x0 + x1 * x1 + x2 * x2 + x3 * x3;
#pragma unroll
    for (int m = 1; m < 64; m <<= 1) {
        s  += __shfl_xor(s,  m, 64);
        s2 += __shfl_xor(s2, m, 64);
    }
    float mean = s * (1.0f / CC);
    float rs = rsqrtf(s2 * (1.0f / CC) - mean * mean + 1e-5f);
    float4 wv = *reinterpret_cast<const float4*>(w  + l * 4);
    float4 bb = *reinterpret_cast<const float4*>(bv + l * 4);
    float n0 = (x0 - mean) * rs * wv.x + bb.x;
    float n1 = (x1 - mean) * rs * wv.y + bb.y;
    float n2 = (x2 - mean) * rs * wv.z + bb.z;
    float n3 = (x3 - mean) * rs * wv.w + bb.w;
    float4 o; o.x = n0; o.y = n1; o.z = n2; o.w = n3;
    *reinterpret_cast<float4*>(xqf + roff) = o;
    ushort4 u; u.x = f2bu(n0); u.y = f2bu(n1); u.z = f2bu(n2); u.w = f2bu(n3);
    *reinterpret_cast<ushort4*>(xqb + roff) = u;
}

// ---------------- KV projection: 512-thread block, 64 rows x 512 cols, A in LDS ----------------
__global__ __launch_bounds__(512)
void gemm_kv(const u16* __restrict__ A, const u16* __restrict__ WT,
             u16* __restrict__ Cb, u16* __restrict__ Cb2, int M)
{
    __shared__ u16 alds[64 * 256];   // 32 KiB
    const int tid = threadIdx.x;
    const int w = tid >> 6, l = tid & 63;
    const int l15 = l & 15, kg = l >> 4;
    const int rowbase = blockIdx.x * 64;
    const f32x4 fz = {0.f, 0.f, 0.f, 0.f};

    {
        const char* gb = (const char*)(A + (size_t)rowbase * CC);
        char* lb = (char*)alds;
#pragma unroll
        for (int j = 0; j < 4; j++) {
            int o = tid * 64 + j * 16;
            short8 v = *reinterpret_cast<const short8*>(gb + o);
            int d = o ^ (((o >> 9) & 7) << 4);
            *reinterpret_cast<short8*>(lb + d) = v;
        }
    }
    __syncthreads();

    const int colbase = w * 64;
    const u16* bp[4];
#pragma unroll
    for (int ni = 0; ni < 4; ni++)
        bp[ni] = WT + (size_t)(colbase + ni * 16 + l15) * CC + kg * 8;

    f32x4 acc[4][4];
#pragma unroll
    for (int mi = 0; mi < 4; mi++)
#pragma unroll
        for (int ni = 0; ni < 4; ni++) acc[mi][ni] = fz;

    const char* lb = (const char*)alds;
    const int sw = (l15 & 7) << 4;
    int abase[4];
#pragma unroll
    for (int mi = 0; mi < 4; mi++) abase[mi] = (mi * 16 + l15) << 9;

#pragma unroll
    for (int ks = 0; ks < 8; ks++) {
        const int koff = ((ks * 64) + (kg * 16)) ^ sw;
        short8 a[4], bfr[4];
#pragma unroll
        for (int mi = 0; mi < 4; mi++)
            a[mi] = *reinterpret_cast<const short8*>(lb + abase[mi] + koff);
#pragma unroll
        for (int ni = 0; ni < 4; ni++)
            bfr[ni] = *reinterpret_cast<const short8*>(bp[ni] + ks * 32);
#pragma unroll
        for (int mi = 0; mi < 4; mi++)
#pragma unroll
            for (int ni = 0; ni < 4; ni++)
                acc[mi][ni] = MFMA16(a[mi], bfr[ni], acc[mi][ni]);
    }

#pragma unroll
    for (int mi = 0; mi < 4; mi++) {
#pragma unroll
        for (int j = 0; j < 4; j++) {
            int r = rowbase + mi * 16 + kg * 4 + j;
            if (r >= M) continue;
#pragma unroll
            for (int ni = 0; ni < 4; ni++) {
                int col = colbase + ni * 16 + l15;
                float v = acc[mi][ni][j];
                if (col < CC) Cb[(size_t)r * CC + col] = f2bu(v);
                else          Cb2[(size_t)r * CC + (col - CC)] = f2bu(v);
            }
        }
    }
}

// ---------------- generic 4-wave MFMA GEMM (MT = row-tile: 64 or 16) ----------------
template<int EPI, int MT>
__global__ __launch_bounds__(256)
void gemm_k(const u16* __restrict__ A, const u16* __restrict__ WT,
            u16* __restrict__ Cb, u16* __restrict__ Cb2, float* __restrict__ Cf,
            const float* __restrict__ basep, const float* __restrict__ gvec,
            float* __restrict__ outp,
            int M, int K, int ldC, int rpb, int bstr)
{
    constexpr int NM = MT / 16;
    const int w = threadIdx.x >> 6, l = threadIdx.x & 63;
    const int l15 = l & 15, kg = l >> 4;
    const int rowbase = blockIdx.x * MT;
    const int colbase = blockIdx.y * 256 + w * 64;
    const short8 z8 = {0, 0, 0, 0, 0, 0, 0, 0};
    const f32x4 fz = {0.f, 0.f, 0.f, 0.f};

    const u16* ap[NM]; bool av[NM];
#pragma unroll
    for (int mi = 0; mi < NM; mi++) {
        int r = rowbase + mi * 16 + l15;
        av[mi] = (r < M);
        int rr = av[mi] ? r : 0;
        size_t ar = (size_t)(rr / rpb) * bstr + (rr % rpb);
        ap[mi] = A + ar * K + kg * 8;
    }
    const u16* bp[4];
#pragma unroll
    for (int ni = 0; ni < 4; ni++) {
        int col = colbase + ni * 16 + l15;
        bp[ni] = WT + (size_t)col * K + kg * 8;
    }
    f32x4 acc[NM][4];
#pragma unroll
    for (int mi = 0; mi < NM; mi++)
#pragma unroll
        for (int ni = 0; ni < 4; ni++) acc[mi][ni] = fz;

    for (int ks = 0; ks < K; ks += 32) {
        short8 a[NM], bfr[4];
#pragma unroll
        for (int mi = 0; mi < NM; mi++)
            a[mi] = av[mi] ? *reinterpret_cast<const short8*>(ap[mi] + ks) : z8;
#pragma unroll
        for (int ni = 0; ni < 4; ni++)
            bfr[ni] = *reinterpret_cast<const short8*>(bp[ni] + ks);
#pragma unroll
        for (int mi = 0; mi < NM; mi++)
#pragma unroll
            for (int ni = 0; ni < 4; ni++)
                acc[mi][ni] = MFMA16(a[mi], bfr[ni], acc[mi][ni]);
    }
#pragma unroll
    for (int mi = 0; mi < NM; mi++) {
#pragma unroll
        for (int j = 0; j < 4; j++) {
            int r = rowbase + mi * 16 + kg * 4 + j;
            if (r >= M) continue;
#pragma unroll
            for (int ni = 0; ni < 4; ni++) {
                int col = colbase + ni * 16 + l15;
                float v = acc[mi][ni][j];
                if (EPI == 0) {
                    if (col < CC) Cb[(size_t)r * ldC + col] = f2bu(v);
                    else          Cb2[(size_t)r * ldC + (col - CC)] = f2bu(v);
                } else if (EPI == 1) {
                    float gl = 0.5f * v * (1.0f + erff(v * 0.70710678118654752f));
                    Cb[(size_t)r * ldC + col] = f2bu(gl);
                } else if (EPI == 2) {
                    Cf[(size_t)r * ldC + col] = v;
                } else {
                    float res = basep[(size_t)r * CC + col] + gvec[col] * v;
                    size_t orow = (size_t)(r / QQ) * NN + (r % QQ);
                    outp[orow * CC + col] = res;
                }
            }
        }
    }
}

// ---------------- flash attention: K via global_load_lds (shared), no-max exp2, pipelined P ----------------
__global__ __launch_bounds__(256)
void attn_k(const u16* __restrict__ qm, const u16* __restrict__ km,
            const u16* __restrict__ vm, float* __restrict__ Op,
            float* __restrict__ lp)
{
    __shared__ u16 klds[2][64 * 32];    // [key][32 u16], source-pre-swizzled (8 KiB)
    __shared__ u16 vt[2][32 * 64];      // [d][key], XOR-swizzled (8 KiB)
    __shared__ u16 plds[4][2][16 * 64]; // per-wave parity-double-buffered P (16 KiB)

    const int bx = blockIdx.x;
    const int split = bx >> 6;
    const int rem = bx & 63;
    const int h = rem >> 3, b = rem & 7;
    const int bh = b * HH + h;
    const int tid = threadIdx.x;
    const int w = tid >> 6, l = tid & 63;
    const int l15 = l & 15, kg = l >> 4;
    const int tstart = split * 64;
    const int nt = (NN - tstart + TSTR - 1) / TSTR;

    const f32x4 fz = {0.f, 0.f, 0.f, 0.f};
    const short os = (short)0x3F80;     // bf16 1.0
    const short8 ones = {os, os, os, os, os, os, os, os};

    const u16* kbase = km + (size_t)b * NN * CC + h * DD;
    const u16* vbase = vm + (size_t)b * NN * CC + h * DD;
    const int vkp = (tid & 31) * 2;
    const int vdg = (tid >> 5) * 4;

    // K staging geometry: wave w covers rows 16w..16w+15; lane -> (row, dest slot)
    const int krow  = (w << 4) + (l >> 2);
    const int kslot = (l & 3) ^ ((krow >> 1) & 3);          // source pre-swizzle
    const u16* ksrc = kbase + (size_t)krow * CC + kslot * 8;

    short8 qfr[5];
#pragma unroll
    for (int qf = 0; qf < 5; qf++) {
        int qrow = w * 80 + qf * 16 + l15;
        int qc = qrow < QQ ? qrow : 0;
        qfr[qf] = *reinterpret_cast<const short8*>(qm + ((size_t)(b * QQ + qc) * CC + h * DD + kg * 8));
    }

    f32x4 o[2][5]; float lpart[5];
#pragma unroll
    for (int qf = 0; qf < 5; qf++) { o[0][qf] = fz; o[1][qf] = fz; lpart[qf] = 0.f; }

    // prologue: issue K(0) -> klds[0]; V(0) -> regs
    gload16(ksrc + (size_t)tstart * CC, (u16*)((char*)klds[0] + (w << 10)));
    ushort4 v0r = *reinterpret_cast<const ushort4*>(vbase + (size_t)(tstart + vkp) * CC + vdg);
    ushort4 v1r = *reinterpret_cast<const ushort4*>(vbase + (size_t)(tstart + vkp + 1) * CC + vdg);

    char* pl = (char*)plds[w];
    const int rdswz = ((l15 << 7) ^ ((l15 & 7) << 4)) + (kg << 4);
    const int wrbase = (l15 << 7) ^ ((l15 & 7) << 4);

    for (int t = 0; t < nt; ++t) {
        const int n0 = tstart + t * TSTR;
        // stage V(t) -> vt[t&1]
        char* vtb = (char*)vt[t & 1];
#pragma unroll
        for (int i = 0; i < 4; i++) {
            int row = vdg + i;
            unsigned int pk2 = (unsigned int)v0r[i] | ((unsigned int)v1r[i] << 16);
            int byteo = ((row << 7) + (vkp << 1)) ^ ((row & 7) << 4);
            *reinterpret_cast<unsigned int*>(vtb + byteo) = pk2;
        }
        __syncthreads();   // drains K(t) vmcnt + V writes

        // issue K(t+1) into klds[(t+1)&1] (in flight across the whole tile body)
        gload16(ksrc + (size_t)(n0 + TSTR) * CC, (u16*)((char*)klds[(t + 1) & 1] + (w << 10)));
        // prefetch V(t+1) into regs
        ushort4 v0n = *reinterpret_cast<const ushort4*>(vbase + (size_t)(n0 + TSTR + vkp) * CC + vdg);
        ushort4 v1n = *reinterpret_cast<const ushort4*>(vbase + (size_t)(n0 + TSTR + vkp + 1) * CC + vdg);

        // K fragments from LDS (once per tile, reused across 5 qf)
        short8 kf[4];
        { const char* klb = (const char*)klds[t & 1];
#pragma unroll
          for (int kb = 0; kb < 4; kb++) {
              int row = kb * 16 + l15;
              int off = (row << 6) + ((kg ^ ((row >> 1) & 3)) << 4);
              kf[kb] = *reinterpret_cast<const short8*>(klb + off);
          } }

        // V^T A-fragments
        short8 va[2][2];
#pragma unroll
        for (int ks = 0; ks < 2; ks++)
#pragma unroll
            for (int dg = 0; dg < 2; dg++) {
                int row = dg * 16 + l15;
                int byteo = ((row << 7) + 64 * ks + 16 * kg) ^ ((row & 7) << 4);
                va[ks][dg] = *reinterpret_cast<const short8*>(vtb + byteo);
            }

        const bool tail = (n0 + 64 > NN);

#pragma unroll
        for (int qf = 0; qf < 5; qf++) {
            short8 bp0, bp1;
            if (qf > 0) {
                const char* plr = pl + (((qf - 1) & 1) << 11);
                bp0 = *reinterpret_cast<const short8*>(plr + rdswz);
                bp1 = *reinterpret_cast<const short8*>(plr + rdswz + 64);
            }
            f32x4 s[4];
            __builtin_amdgcn_s_setprio(1);
#pragma unroll
            for (int kb = 0; kb < 4; kb++)
                s[kb] = MFMA16(kf[kb], qfr[qf], fz);
            __builtin_amdgcn_s_setprio(0);
            char* plw = pl + ((qf & 1) << 11);
#pragma unroll
            for (int kb = 0; kb < 4; kb++) {
                float p0 = exp2f(s[kb][0]);
                float p1 = exp2f(s[kb][1]);
                float p2 = exp2f(s[kb][2]);
                float p3 = exp2f(s[kb][3]);
                if (tail) {
                    int kbase2 = n0 + 16 * kb + 4 * kg;
                    if (kbase2 + 0 >= NN) p0 = 0.f;
                    if (kbase2 + 1 >= NN) p1 = 0.f;
                    if (kbase2 + 2 >= NN) p2 = 0.f;
                    if (kbase2 + 3 >= NN) p3 = 0.f;
                }
                int byte0 = wrbase + ((16 * kb + 4 * kg) << 1);
                *reinterpret_cast<unsigned int*>(plw + byte0)     = cvtpk(p0, p1);
                *reinterpret_cast<unsigned int*>(plw + byte0 + 4) = cvtpk(p2, p3);
            }
            if (qf > 0) {
                __builtin_amdgcn_s_setprio(1);
                o[0][qf - 1] = MFMA16(va[0][0], bp0, o[0][qf - 1]);
                o[1][qf - 1] = MFMA16(va[0][1], bp0, o[1][qf - 1]);
                o[0][qf - 1] = MFMA16(va[1][0], bp1, o[0][qf - 1]);
                o[1][qf - 1] = MFMA16(va[1][1], bp1, o[1][qf - 1]);
                f32x4 tsum = MFMA16(ones, bp0, fz);
                tsum = MFMA16(ones, bp1, tsum);
                __builtin_amdgcn_s_setprio(0);
                lpart[qf - 1] += tsum[0];
            }
        }
        {
            const char* plr = pl + 0;
            short8 bp0 = *reinterpret_cast<const short8*>(plr + rdswz);
            short8 bp1 = *reinterpret_cast<const short8*>(plr + rdswz + 64);
            __builtin_amdgcn_s_setprio(1);
            o[0][4] = MFMA16(va[0][0], bp0, o[0][4]);
            o[1][4] = MFMA16(va[0][1], bp0, o[1][4]);
            o[0][4] = MFMA16(va[1][0], bp1, o[0][4]);
            o[1][4] = MFMA16(va[1][1], bp1, o[1][4]);
            f32x4 tsum = MFMA16(ones, bp0, fz);
            tsum = MFMA16(ones, bp1, tsum);
            __builtin_amdgcn_s_setprio(0);
            lpart[4] += tsum[0];
        }
        v0r = v0n; v1r = v1n;
    }

    size_t pb = (size_t)(split * 64 + bh) * QQ;
#pragma unroll
    for (int qf = 0; qf < 5; qf++) {
        int q = w * 80 + qf * 16 + l15;
        if (q >= QQ) continue;
        size_t pr = pb + q;
        if (kg == 0) lp[pr] = lpart[qf];
        *reinterpret_cast<f32x4*>(Op + pr * DD + kg * 4)      = o[0][qf];
        *reinterpret_cast<f32x4*>(Op + pr * DD + 16 + kg * 4) = o[1][qf];
    }
}

// ---------------- combine split partials ----------------
__global__ __launch_bounds__(256)
void comb_k(const float* __restrict__ Op, const float* __restrict__ lp, u16* __restrict__ ao)
{
    int g = blockIdx.x * 256 + threadIdx.x;    // 2400 rows * 8 threads
    int d4 = (g & 7) * 4;
    int row = g >> 3;
    int bh = row / QQ, qq = row - bh * QQ;
    int b = bh >> 3, h = bh & 7;
    float L = 0.f, a0 = 0.f, a1 = 0.f, a2 = 0.f, a3 = 0.f;
#pragma unroll
    for (int s = 0; s < NSPLIT; s++) {
        size_t pr = (size_t)(s * 64 + bh) * QQ + qq;
        L += lp[pr];
        float4 ov = *reinterpret_cast<const float4*>(Op + pr * DD + d4);
        a0 += ov.x; a1 += ov.y; a2 += ov.z; a3 += ov.w;
    }
    float inv = 1.0f / L;
    ushort4 u;
    u.x = f2bu(a0 * inv); u.y = f2bu(a1 * inv); u.z = f2bu(a2 * inv); u.w = f2bu(a3 * inv);
    *reinterpret_cast<ushort4*>(ao + ((size_t)(b * QQ + qq) * CC + h * DD + d4)) = u;
}

// ---------------- launch ----------------
extern "C" void kernel_launch(void* const* d_in, const int* in_sizes, int n_in,
                              void* d_out, int out_size, void* d_ws, size_t ws_size,
                              hipStream_t stream)
{
    (void)in_sizes; (void)n_in; (void)out_size; (void)ws_size;
    const float* x    = (const float*)d_in[0];
    const float* Wq   = (const float*)d_in[1];
    const float* Wk   = (const float*)d_in[2];
    const float* Wv   = (const float*)d_in[3];
    const float* Wp   = (const float*)d_in[4];
    const float* W1   = (const float*)d_in[5];
    const float* W2   = (const float*)d_in[6];
    const float* ln1w = (const float*)d_in[7];
    const float* ln1b = (const float*)d_in[8];
    const float* ln2w = (const float*)d_in[9];
    const float* ln2b = (const float*)d_in[10];
    const float* g1   = (const float*)d_in[11];
    const float* g2   = (const float*)d_in[12];
    float* out = (float*)d_out;

    char* p = (char*)d_ws;
    auto alloc = [&](size_t bytes) { char* r = p; p += (bytes + 255) & ~(size_t)255; return r; };

    const size_t MKV = (size_t)BB * NN;        // 69600
    const size_t MQ  = (size_t)BB * QQ;        // 2400

    u16* WqT  = (u16*)alloc((size_t)CC * CC * 2);
    u16* WkvT = (u16*)alloc((size_t)CC * CC * 2 * 2);   // K cols then V cols
    u16* WpT  = (u16*)alloc((size_t)CC * CC * 2);
    u16* W1T  = (u16*)alloc((size_t)CC * HIDN * 2);
    u16* W2T  = (u16*)alloc((size_t)HIDN * CC * 2);
    u16* xn   = (u16*)alloc((MKV + 64) * CC * 2);
    u16* kbf  = (u16*)alloc((MKV + KSLACK) * CC * 2);
    u16* vbf  = (u16*)alloc((MKV + KSLACK) * CC * 2);
    u16* qbf  = (u16*)alloc(MQ * CC * 2);
    u16* aob  = (u16*)alloc(MQ * CC * 2);
    u16* xqb  = (u16*)alloc(MQ * CC * 2);
    u16* h1   = (u16*)alloc(MQ * HIDN * 2);
    float* pd  = (float*)alloc(MQ * CC * 4);
    float* xqf = (float*)alloc(MQ * CC * 4);
    float* Op  = (float*)alloc((size_t)NSPLIT * 64 * QQ * DD * 4);
    float* lp  = (float*)alloc((size_t)NSPLIT * 64 * QQ * 4);

    const float qscale = 0.17677669529663687f * 1.4426950408889634f;

    wprep_t<<<192, 256, 0, stream>>>(Wq, Wk, Wv, Wp, W1, W2, WqT, qscale);

    ln1_k<<<(int)(MKV / 4), 256, 0, stream>>>(x, ln1w, ln1b, g1, xn, out);

    gemm_kv<<<1088, 512, 0, stream>>>(xn, WkvT, kbf, vbf, (int)MKV);
    gemm_k<0, 16><<<dim3(150, 1), 256, 0, stream>>>(xn, WqT, qbf, nullptr, nullptr, nullptr, nullptr, nullptr,
                                                    (int)MQ, CC, CC, QQ, NN);

    attn_k<<<64 * NSPLIT, 256, 0, stream>>>(qbf, kbf, vbf, Op, lp);
    comb_k<<<(int)(MQ * 8 / 256), 256, 0, stream>>>(Op, lp, aob);

    gemm_k<2, 16><<<dim3(150, 1), 256, 0, stream>>>(aob, WpT, nullptr, nullptr, pd, nullptr, nullptr, nullptr,
                                                    (int)MQ, CC, CC, (int)MQ, 0);
    ln2_k<<<(int)(MQ / 4), 256, 0, stream>>>(x, pd, g1, ln2w, ln2b, xqf, xqb);

    gemm_k<1, 16><<<dim3(150, 4), 256, 0, stream>>>(xqb, W1T, h1, nullptr, nullptr, nullptr, nullptr, nullptr,
                                                    (int)MQ, CC, HIDN, (int)MQ, 0);
    gemm_k<3, 16><<<dim3(150, 1), 256, 0, stream>>>(h1, W2T, nullptr, nullptr, nullptr, xqf, g2, out,
                                                    (int)MQ, HIDN, CC, (int)MQ, 0);
}

// Round 11
// 223.385 us; speedup vs baseline: 1.0209x; 1.0209x over previous
//
#include <hip/hip_runtime.h>

#define BB 8
#define NN 8700
#define CC 256
#define QQ 300
#define HH 8
#define DD 32
#define HIDN 1024
#define NSPLIT 16
#define TSTR (NSPLIT * 64)
#define KSLACK 1536

typedef unsigned short u16;
typedef __attribute__((ext_vector_type(8))) short short8;
typedef __attribute__((ext_vector_type(4))) float f32x4;

#define MFMA16(a, b, c) __builtin_amdgcn_mfma_f32_16x16x32_bf16((a), (b), (c), 0, 0, 0)

__device__ __forceinline__ unsigned int cvtpk(float lo, float hi) {
    unsigned int r;
    asm("v_cvt_pk_bf16_f32 %0, %1, %2" : "=v"(r) : "v"(lo), "v"(hi));
    return r;
}
__device__ __forceinline__ u16 f2b_hw(float f) { return (u16)cvtpk(f, 0.f); }
__device__ __forceinline__ float b2f(u16 u) {
    unsigned int x = ((unsigned int)u) << 16;
    return __builtin_bit_cast(float, x);
}
__device__ __forceinline__ void gload16(const u16* g, u16* l) {
    __builtin_amdgcn_global_load_lds(
        (const __attribute__((address_space(1))) void*)g,
        (__attribute__((address_space(3))) void*)l, 16, 0, 0);
}

// ---------------- tiled weight transpose: coalesced read + coalesced write ----------------
__global__ __launch_bounds__(256)
void wprep_t(const float* __restrict__ Wq, const float* __restrict__ Wk,
             const float* __restrict__ Wv, const float* __restrict__ Wp,
             const float* __restrict__ W1, const float* __restrict__ W2,
             u16* __restrict__ dst, float qscale)
{
    __shared__ u16 tl[64][66];
    int bid = blockIdx.x;
    const float* src; int K, N, tr, tc; size_t dof; float sc = 1.f;
    if (bid < 64) {
        int mat = bid >> 4, ti = bid & 15;
        src = (mat == 0) ? Wq : (mat == 1) ? Wk : (mat == 2) ? Wv : Wp;
        K = 256; N = 256; tr = ti >> 2; tc = ti & 3;
        dof = (size_t)mat * 65536;
        if (mat == 0) sc = qscale;
    } else if (bid < 128) {
        int ti = bid - 64; src = W1; K = 256; N = 1024; tr = ti >> 4; tc = ti & 15; dof = 262144;
    } else {
        int ti = bid - 128; src = W2; K = 1024; N = 256; tr = ti >> 2; tc = ti & 3; dof = 524288;
    }
    int tid = threadIdx.x;
    int jj = tid & 63;
    int i0 = tid >> 6;
#pragma unroll
    for (int ii = 0; ii < 16; ii++) {
        int kk = i0 * 16 + ii;
        float v = src[(size_t)(tr * 64 + kk) * N + tc * 64 + jj] * sc;
        tl[kk][jj] = f2b_hw(v);
    }
    __syncthreads();
#pragma unroll
    for (int ii = 0; ii < 16; ii++) {
        int nn = i0 * 16 + ii;
        dst[dof + (size_t)(tc * 64 + nn) * K + tr * 64 + jj] = tl[jj][nn];
    }
}

// ---------------- LN1 + context-token output ----------------
__global__ __launch_bounds__(256)
void ln1_k(const float* __restrict__ x, const float* __restrict__ w,
           const float* __restrict__ bv, const float* __restrict__ g1,
           u16* __restrict__ xn, float* __restrict__ out)
{
    int row = blockIdx.x * 4 + (threadIdx.x >> 6);
    int l = threadIdx.x & 63;
    size_t base = (size_t)row * CC + l * 4;
    float4 xv = *reinterpret_cast<const float4*>(x + base);
    float s  = xv.x + xv.y + xv.z + xv.w;
    float s2 = xv.x * xv.x + xv.y * xv.y + xv.z * xv.z + xv.w * xv.w;
#pragma unroll
    for (int m = 1; m < 64; m <<= 1) {
        s  += __shfl_xor(s,  m, 64);
        s2 += __shfl_xor(s2, m, 64);
    }
    float mean = s * (1.0f / CC);
    float rs = rsqrtf(s2 * (1.0f / CC) - mean * mean + 1e-5f);
    float4 wv = *reinterpret_cast<const float4*>(w  + l * 4);
    float4 bb = *reinterpret_cast<const float4*>(bv + l * 4);
    float n0 = (xv.x - mean) * rs * wv.x + bb.x;
    float n1 = (xv.y - mean) * rs * wv.y + bb.y;
    float n2 = (xv.z - mean) * rs * wv.z + bb.z;
    float n3 = (xv.w - mean) * rs * wv.w + bb.w;
    uint2 u; u.x = cvtpk(n0, n1); u.y = cvtpk(n2, n3);
    *reinterpret_cast<uint2*>(xn + base) = u;
    int n = row % NN;
    if (n >= QQ) {
        float4 gv = *reinterpret_cast<const float4*>(g1 + l * 4);
        float4 o;
        o.x = 2.0f * (xv.x + gv.x * n0);
        o.y = 2.0f * (xv.y + gv.y * n1);
        o.z = 2.0f * (xv.z + gv.z * n2);
        o.w = 2.0f * (xv.w + gv.w * n3);
        *reinterpret_cast<float4*>(out + base) = o;
    }
}

// ---------------- residual + LN2 for query tokens ----------------
__global__ __launch_bounds__(256)
void ln2_k(const float* __restrict__ x, const float* __restrict__ pd,
           const float* __restrict__ g1, const float* __restrict__ w,
           const float* __restrict__ bv, float* __restrict__ xqf, u16* __restrict__ xqb)
{
    int r = blockIdx.x * 4 + (threadIdx.x >> 6);
    int l = threadIdx.x & 63;
    int b = r / QQ, n = r - b * QQ;
    size_t xoff = ((size_t)b * NN + n) * CC + l * 4;
    size_t roff = (size_t)r * CC + l * 4;
    float4 xv = *reinterpret_cast<const float4*>(x + xoff);
    float4 pv = *reinterpret_cast<const float4*>(pd + roff);
    float4 gv = *reinterpret_cast<const float4*>(g1 + l * 4);
    float x0 = xv.x + gv.x * pv.x;
    float x1 = xv.y + gv.y * pv.y;
    float x2 = xv.z + gv.z * pv.z;
    float x3 = xv.w + gv.w * pv.w;
    float s  = x0 + x1 + x2 + x3;
    float s2 = x0 * x0 + x1 * x1 + x2 * x2 + x3 * x3;
#pragma unroll
    for (int m = 1; m < 64; m <<= 1) {
        s  += __shfl_xor(s,  m, 64);
        s2 += __shfl_xor(s2, m, 64);
    }
    float mean = s * (1.0f / CC);
    float rs = rsqrtf(s2 * (1.0f / CC) - mean * mean + 1e-5f);
    float4 wv = *reinterpret_cast<const float4*>(w  + l * 4);
    float4 bb = *reinterpret_cast<const float4*>(bv + l * 4);
    float n0 = (x0 - mean) * rs * wv.x + bb.x;
    float n1 = (x1 - mean) * rs * wv.y + bb.y;
    float n2 = (x2 - mean) * rs * wv.z + bb.z;
    float n3 = (x3 - mean) * rs * wv.w + bb.w;
    float4 o; o.x = n0; o.y = n1; o.z = n2; o.w = n3;
    *reinterpret_cast<float4*>(xqf + roff) = o;
    uint2 u; u.x = cvtpk(n0, n1); u.y = cvtpk(n2, n3);
    *reinterpret_cast<uint2*>(xqb + roff) = u;
}

// ---------------- KV projection: swapped-operand MFMA, vectorized epilogue ----------------
// D[row=c][col=r]: thread holds 4 CONSECUTIVE output cols (kg*4+j) at row l15.
__global__ __launch_bounds__(512)
void gemm_kv(const u16* __restrict__ A, const u16* __restrict__ WT,
             u16* __restrict__ Cb, u16* __restrict__ Cb2, int M)
{
    __shared__ u16 alds[64 * 256];   // 32 KiB
    const int tid = threadIdx.x;
    const int w = tid >> 6, l = tid & 63;
    const int l15 = l & 15, kg = l >> 4;
    const int rowbase = blockIdx.x * 64;
    const f32x4 fz = {0.f, 0.f, 0.f, 0.f};

    {
        const char* gb = (const char*)(A + (size_t)rowbase * CC);
        char* lb = (char*)alds;
#pragma unroll
        for (int j = 0; j < 4; j++) {
            int o = tid * 64 + j * 16;
            short8 v = *reinterpret_cast<const short8*>(gb + o);
            int d = o ^ (((o >> 9) & 7) << 4);
            *reinterpret_cast<short8*>(lb + d) = v;
        }
    }
    __syncthreads();

    const int colbase = w * 64;
    const u16* bp[4];
#pragma unroll
    for (int ni = 0; ni < 4; ni++)
        bp[ni] = WT + (size_t)(colbase + ni * 16 + l15) * CC + kg * 8;

    f32x4 acc[4][4];
#pragma unroll
    for (int mi = 0; mi < 4; mi++)
#pragma unroll
        for (int ni = 0; ni < 4; ni++) acc[mi][ni] = fz;

    const char* lb = (const char*)alds;
    const int sw = (l15 & 7) << 4;
    int abase[4];
#pragma unroll
    for (int mi = 0; mi < 4; mi++) abase[mi] = (mi * 16 + l15) << 9;

#pragma unroll
    for (int ks = 0; ks < 8; ks++) {
        const int koff = ((ks * 64) + (kg * 16)) ^ sw;
        short8 a[4], bfr[4];
#pragma unroll
        for (int mi = 0; mi < 4; mi++)
            a[mi] = *reinterpret_cast<const short8*>(lb + abase[mi] + koff);
#pragma unroll
        for (int ni = 0; ni < 4; ni++)
            bfr[ni] = *reinterpret_cast<const short8*>(bp[ni] + ks * 32);
#pragma unroll
        for (int mi = 0; mi < 4; mi++)
#pragma unroll
            for (int ni = 0; ni < 4; ni++)
                acc[mi][ni] = MFMA16(bfr[ni], a[mi], acc[mi][ni]);   // swapped operands
    }

#pragma unroll
    for (int mi = 0; mi < 4; mi++) {
        int r = rowbase + mi * 16 + l15;
        if (r >= M) continue;
#pragma unroll
        for (int ni = 0; ni < 4; ni++) {
            int col0 = colbase + ni * 16 + kg * 4;
            f32x4 v = acc[mi][ni];
            uint2 pk; pk.x = cvtpk(v[0], v[1]); pk.y = cvtpk(v[2], v[3]);
            if (col0 < CC) *reinterpret_cast<uint2*>(Cb  + (size_t)r * CC + col0)        = pk;
            else           *reinterpret_cast<uint2*>(Cb2 + (size_t)r * CC + (col0 - CC)) = pk;
        }
    }
}

// ---------------- generic 4-wave MFMA GEMM (swapped operands, vectorized epilogue) ----------------
template<int EPI, int MT>
__global__ __launch_bounds__(256)
void gemm_k(const u16* __restrict__ A, const u16* __restrict__ WT,
            u16* __restrict__ Cb, u16* __restrict__ Cb2, float* __restrict__ Cf,
            const float* __restrict__ basep, const float* __restrict__ gvec,
            float* __restrict__ outp,
            int M, int K, int ldC, int rpb, int bstr)
{
    constexpr int NM = MT / 16;
    const int w = threadIdx.x >> 6, l = threadIdx.x & 63;
    const int l15 = l & 15, kg = l >> 4;
    const int rowbase = blockIdx.x * MT;
    const int colbase = blockIdx.y * 256 + w * 64;
    const short8 z8 = {0, 0, 0, 0, 0, 0, 0, 0};
    const f32x4 fz = {0.f, 0.f, 0.f, 0.f};

    const u16* ap[NM]; bool av[NM];
#pragma unroll
    for (int mi = 0; mi < NM; mi++) {
        int r = rowbase + mi * 16 + l15;
        av[mi] = (r < M);
        int rr = av[mi] ? r : 0;
        size_t ar = (size_t)(rr / rpb) * bstr + (rr % rpb);
        ap[mi] = A + ar * K + kg * 8;
    }
    const u16* bp[4];
#pragma unroll
    for (int ni = 0; ni < 4; ni++) {
        int col = colbase + ni * 16 + l15;
        bp[ni] = WT + (size_t)col * K + kg * 8;
    }
    f32x4 acc[NM][4];
#pragma unroll
    for (int mi = 0; mi < NM; mi++)
#pragma unroll
        for (int ni = 0; ni < 4; ni++) acc[mi][ni] = fz;

    for (int ks = 0; ks < K; ks += 32) {
        short8 a[NM], bfr[4];
#pragma unroll
        for (int mi = 0; mi < NM; mi++)
            a[mi] = av[mi] ? *reinterpret_cast<const short8*>(ap[mi] + ks) : z8;
#pragma unroll
        for (int ni = 0; ni < 4; ni++)
            bfr[ni] = *reinterpret_cast<const short8*>(bp[ni] + ks);
#pragma unroll
        for (int mi = 0; mi < NM; mi++)
#pragma unroll
            for (int ni = 0; ni < 4; ni++)
                acc[mi][ni] = MFMA16(bfr[ni], a[mi], acc[mi][ni]);   // swapped operands
    }
#pragma unroll
    for (int mi = 0; mi < NM; mi++) {
        int r = rowbase + mi * 16 + l15;
        if (r >= M) continue;
#pragma unroll
        for (int ni = 0; ni < 4; ni++) {
            int col0 = colbase + ni * 16 + kg * 4;
            f32x4 v = acc[mi][ni];
            if (EPI == 0) {
                uint2 pk; pk.x = cvtpk(v[0], v[1]); pk.y = cvtpk(v[2], v[3]);
                if (col0 < CC) *reinterpret_cast<uint2*>(Cb  + (size_t)r * ldC + col0)        = pk;
                else           *reinterpret_cast<uint2*>(Cb2 + (size_t)r * ldC + (col0 - CC)) = pk;
            } else if (EPI == 1) {
                float g0 = 0.5f * v[0] * (1.0f + erff(v[0] * 0.70710678118654752f));
                float g1 = 0.5f * v[1] * (1.0f + erff(v[1] * 0.70710678118654752f));
                float g2 = 0.5f * v[2] * (1.0f + erff(v[2] * 0.70710678118654752f));
                float g3 = 0.5f * v[3] * (1.0f + erff(v[3] * 0.70710678118654752f));
                uint2 pk; pk.x = cvtpk(g0, g1); pk.y = cvtpk(g2, g3);
                *reinterpret_cast<uint2*>(Cb + (size_t)r * ldC + col0) = pk;
            } else if (EPI == 2) {
                float4 o; o.x = v[0]; o.y = v[1]; o.z = v[2]; o.w = v[3];
                *reinterpret_cast<float4*>(Cf + (size_t)r * ldC + col0) = o;
            } else {
                float4 xv = *reinterpret_cast<const float4*>(basep + (size_t)r * CC + col0);
                float4 gv = *reinterpret_cast<const float4*>(gvec + col0);
                float4 o;
                o.x = xv.x + gv.x * v[0];
                o.y = xv.y + gv.y * v[1];
                o.z = xv.z + gv.z * v[2];
                o.w = xv.w + gv.w * v[3];
                size_t orow = (size_t)(r / QQ) * NN + (r % QQ);
                *reinterpret_cast<float4*>(outp + orow * CC + col0) = o;
            }
        }
    }
}

// ---------------- flash attention: K via global_load_lds, no-max exp2, pipelined P, bf16 Op ----------------
__global__ __launch_bounds__(256)
void attn_k(const u16* __restrict__ qm, const u16* __restrict__ km,
            const u16* __restrict__ vm, u16* __restrict__ Opb,
            float* __restrict__ lp)
{
    __shared__ u16 klds[2][64 * 32];    // [key][32 u16], source-pre-swizzled (8 KiB)
    __shared__ u16 vt[2][32 * 64];      // [d][key], XOR-swizzled (8 KiB)
    __shared__ u16 plds[4][2][16 * 64]; // per-wave parity-double-buffered P (16 KiB)

    const int bx = blockIdx.x;
    const int split = bx >> 6;
    const int rem = bx & 63;
    const int h = rem >> 3, b = rem & 7;
    const int bh = b * HH + h;
    const int tid = threadIdx.x;
    const int w = tid >> 6, l = tid & 63;
    const int l15 = l & 15, kg = l >> 4;
    const int tstart = split * 64;
    const int nt = (NN - tstart + TSTR - 1) / TSTR;

    const f32x4 fz = {0.f, 0.f, 0.f, 0.f};
    const short os = (short)0x3F80;     // bf16 1.0
    const short8 ones = {os, os, os, os, os, os, os, os};

    const u16* kbase = km + (size_t)b * NN * CC + h * DD;
    const u16* vbase = vm + (size_t)b * NN * CC + h * DD;
    const int vkp = (tid & 31) * 2;
    const int vdg = (tid >> 5) * 4;

    const int krow  = (w << 4) + (l >> 2);
    const int kslot = (l & 3) ^ ((krow >> 1) & 3);
    const u16* ksrc = kbase + (size_t)krow * CC + kslot * 8;

    short8 qfr[5];
#pragma unroll
    for (int qf = 0; qf < 5; qf++) {
        int qrow = w * 80 + qf * 16 + l15;
        int qc = qrow < QQ ? qrow : 0;
        qfr[qf] = *reinterpret_cast<const short8*>(qm + ((size_t)(b * QQ + qc) * CC + h * DD + kg * 8));
    }

    f32x4 o[2][5]; float lpart[5];
#pragma unroll
    for (int qf = 0; qf < 5; qf++) { o[0][qf] = fz; o[1][qf] = fz; lpart[qf] = 0.f; }

    gload16(ksrc + (size_t)tstart * CC, (u16*)((char*)klds[0] + (w << 10)));
    ushort4 v0r = *reinterpret_cast<const ushort4*>(vbase + (size_t)(tstart + vkp) * CC + vdg);
    ushort4 v1r = *reinterpret_cast<const ushort4*>(vbase + (size_t)(tstart + vkp + 1) * CC + vdg);

    char* pl = (char*)plds[w];
    const int rdswz = ((l15 << 7) ^ ((l15 & 7) << 4)) + (kg << 4);
    const int wrbase = (l15 << 7) ^ ((l15 & 7) << 4);

    for (int t = 0; t < nt; ++t) {
        const int n0 = tstart + t * TSTR;
        char* vtb = (char*)vt[t & 1];
#pragma unroll
        for (int i = 0; i < 4; i++) {
            int row = vdg + i;
            unsigned int pk2 = (unsigned int)v0r[i] | ((unsigned int)v1r[i] << 16);
            int byteo = ((row << 7) + (vkp << 1)) ^ ((row & 7) << 4);
            *reinterpret_cast<unsigned int*>(vtb + byteo) = pk2;
        }
        __syncthreads();   // drains K(t) vmcnt + V writes

        gload16(ksrc + (size_t)(n0 + TSTR) * CC, (u16*)((char*)klds[(t + 1) & 1] + (w << 10)));
        ushort4 v0n = *reinterpret_cast<const ushort4*>(vbase + (size_t)(n0 + TSTR + vkp) * CC + vdg);
        ushort4 v1n = *reinterpret_cast<const ushort4*>(vbase + (size_t)(n0 + TSTR + vkp + 1) * CC + vdg);

        short8 kf[4];
        { const char* klb = (const char*)klds[t & 1];
#pragma unroll
          for (int kb = 0; kb < 4; kb++) {
              int row = kb * 16 + l15;
              int off = (row << 6) + ((kg ^ ((row >> 1) & 3)) << 4);
              kf[kb] = *reinterpret_cast<const short8*>(klb + off);
          } }

        short8 va[2][2];
#pragma unroll
        for (int ks = 0; ks < 2; ks++)
#pragma unroll
            for (int dg = 0; dg < 2; dg++) {
                int row = dg * 16 + l15;
                int byteo = ((row << 7) + 64 * ks + 16 * kg) ^ ((row & 7) << 4);
                va[ks][dg] = *reinterpret_cast<const short8*>(vtb + byteo);
            }

        const bool tail = (n0 + 64 > NN);

#pragma unroll
        for (int qf = 0; qf < 5; qf++) {
            short8 bp0, bp1;
            if (qf > 0) {
                const char* plr = pl + (((qf - 1) & 1) << 11);
                bp0 = *reinterpret_cast<const short8*>(plr + rdswz);
                bp1 = *reinterpret_cast<const short8*>(plr + rdswz + 64);
            }
            f32x4 s[4];
            __builtin_amdgcn_s_setprio(1);
#pragma unroll
            for (int kb = 0; kb < 4; kb++)
                s[kb] = MFMA16(kf[kb], qfr[qf], fz);
            __builtin_amdgcn_s_setprio(0);
            char* plw = pl + ((qf & 1) << 11);
#pragma unroll
            for (int kb = 0; kb < 4; kb++) {
                float p0 = exp2f(s[kb][0]);
                float p1 = exp2f(s[kb][1]);
                float p2 = exp2f(s[kb][2]);
                float p3 = exp2f(s[kb][3]);
                if (tail) {
                    int kbase2 = n0 + 16 * kb + 4 * kg;
                    if (kbase2 + 0 >= NN) p0 = 0.f;
                    if (kbase2 + 1 >= NN) p1 = 0.f;
                    if (kbase2 + 2 >= NN) p2 = 0.f;
                    if (kbase2 + 3 >= NN) p3 = 0.f;
                }
                uint2 pw; pw.x = cvtpk(p0, p1); pw.y = cvtpk(p2, p3);
                *reinterpret_cast<uint2*>(plw + (wrbase + ((16 * kb + 4 * kg) << 1))) = pw;
            }
            if (qf > 0) {
                __builtin_amdgcn_s_setprio(1);
                o[0][qf - 1] = MFMA16(va[0][0], bp0, o[0][qf - 1]);
                o[1][qf - 1] = MFMA16(va[0][1], bp0, o[1][qf - 1]);
                o[0][qf - 1] = MFMA16(va[1][0], bp1, o[0][qf - 1]);
                o[1][qf - 1] = MFMA16(va[1][1], bp1, o[1][qf - 1]);
                f32x4 tsum = MFMA16(ones, bp0, fz);
                tsum = MFMA16(ones, bp1, tsum);
                __builtin_amdgcn_s_setprio(0);
                lpart[qf - 1] += tsum[0];
            }
        }
        {
            const char* plr = pl + 0;
            short8 bp0 = *reinterpret_cast<const short8*>(plr + rdswz);
            short8 bp1 = *reinterpret_cast<const short8*>(plr + rdswz + 64);
            __builtin_amdgcn_s_setprio(1);
            o[0][4] = MFMA16(va[0][0], bp0, o[0][4]);
            o[1][4] = MFMA16(va[0][1], bp0, o[1][4]);
            o[0][4] = MFMA16(va[1][0], bp1, o[0][4]);
            o[1][4] = MFMA16(va[1][1], bp1, o[1][4]);
            f32x4 tsum = MFMA16(ones, bp0, fz);
            tsum = MFMA16(ones, bp1, tsum);
            __builtin_amdgcn_s_setprio(0);
            lpart[4] += tsum[0];
        }
        v0r = v0n; v1r = v1n;
    }

    size_t pb = (size_t)(split * 64 + bh) * QQ;
#pragma unroll
    for (int qf = 0; qf < 5; qf++) {
        int q = w * 80 + qf * 16 + l15;
        if (q >= QQ) continue;
        size_t pr = pb + q;
        if (kg == 0) lp[pr] = lpart[qf];
        uint2 w0; w0.x = cvtpk(o[0][qf][0], o[0][qf][1]); w0.y = cvtpk(o[0][qf][2], o[0][qf][3]);
        uint2 w1; w1.x = cvtpk(o[1][qf][0], o[1][qf][1]); w1.y = cvtpk(o[1][qf][2], o[1][qf][3]);
        *reinterpret_cast<uint2*>(Opb + pr * DD + kg * 4)      = w0;
        *reinterpret_cast<uint2*>(Opb + pr * DD + 16 + kg * 4) = w1;
    }
}

// ---------------- combine split partials (bf16 Op, plain sums) ----------------
__global__ __launch_bounds__(256)
void comb_k(const u16* __restrict__ Opb, const float* __restrict__ lp, u16* __restrict__ ao)
{
    int g = blockIdx.x * 256 + threadIdx.x;    // 2400 rows * 8 threads
    int d4 = (g & 7) * 4;
    int row = g >> 3;
    int bh = row / QQ, qq = row - bh * QQ;
    int b = bh >> 3, h = bh & 7;
    float L = 0.f, a0 = 0.f, a1 = 0.f, a2 = 0.f, a3 = 0.f;
#pragma unroll
    for (int s = 0; s < NSPLIT; s++) {
        size_t pr = (size_t)(s * 64 + bh) * QQ + qq;
        L += lp[pr];
        ushort4 ov = *reinterpret_cast<const ushort4*>(Opb + pr * DD + d4);
        a0 += b2f(ov.x); a1 += b2f(ov.y); a2 += b2f(ov.z); a3 += b2f(ov.w);
    }
    float inv = 1.0f / L;
    uint2 u; u.x = cvtpk(a0 * inv, a1 * inv); u.y = cvtpk(a2 * inv, a3 * inv);
    *reinterpret_cast<uint2*>(ao + ((size_t)(b * QQ + qq) * CC + h * DD + d4)) = u;
}

// ---------------- launch ----------------
extern "C" void kernel_launch(void* const* d_in, const int* in_sizes, int n_in,
                              void* d_out, int out_size, void* d_ws, size_t ws_size,
                              hipStream_t stream)
{
    (void)in_sizes; (void)n_in; (void)out_size; (void)ws_size;
    const float* x    = (const float*)d_in[0];
    const float* Wq   = (const float*)d_in[1];
    const float* Wk   = (const float*)d_in[2];
    const float* Wv   = (const float*)d_in[3];
    const float* Wp   = (const float*)d_in[4];
    const float* W1   = (const float*)d_in[5];
    const float* W2   = (const float*)d_in[6];
    const float* ln1w = (const float*)d_in[7];
    const float* ln1b = (const float*)d_in[8];
    const float* ln2w = (const float*)d_in[9];
    const float* ln2b = (const float*)d_in[10];
    const float* g1   = (const float*)d_in[11];
    const float* g2   = (const float*)d_in[12];
    float* out = (float*)d_out;

    char* p = (char*)d_ws;
    auto alloc = [&](size_t bytes) { char* r = p; p += (bytes + 255) & ~(size_t)255; return r; };

    const size_t MKV = (size_t)BB * NN;        // 69600
    const size_t MQ  = (size_t)BB * QQ;        // 2400

    u16* WqT  = (u16*)alloc((size_t)CC * CC * 2);
    u16* WkvT = (u16*)alloc((size_t)CC * CC * 2 * 2);   // K cols then V cols
    u16* WpT  = (u16*)alloc((size_t)CC * CC * 2);
    u16* W1T  = (u16*)alloc((size_t)CC * HIDN * 2);
    u16* W2T  = (u16*)alloc((size_t)HIDN * CC * 2);
    u16* xn   = (u16*)alloc((MKV + 64) * CC * 2);
    u16* kbf  = (u16*)alloc((MKV + KSLACK) * CC * 2);
    u16* vbf  = (u16*)alloc((MKV + KSLACK) * CC * 2);
    u16* qbf  = (u16*)alloc(MQ * CC * 2);
    u16* aob  = (u16*)alloc(MQ * CC * 2);
    u16* xqb  = (u16*)alloc(MQ * CC * 2);
    u16* h1   = (u16*)alloc(MQ * HIDN * 2);
    float* pd  = (float*)alloc(MQ * CC * 4);
    float* xqf = (float*)alloc(MQ * CC * 4);
    u16* Opb  = (u16*)alloc((size_t)NSPLIT * 64 * QQ * DD * 2);
    float* lp  = (float*)alloc((size_t)NSPLIT * 64 * QQ * 4);

    const float qscale = 0.17677669529663687f * 1.4426950408889634f;

    wprep_t<<<192, 256, 0, stream>>>(Wq, Wk, Wv, Wp, W1, W2, WqT, qscale);

    ln1_k<<<(int)(MKV / 4), 256, 0, stream>>>(x, ln1w, ln1b, g1, xn, out);

    gemm_kv<<<1088, 512, 0, stream>>>(xn, WkvT, kbf, vbf, (int)MKV);
    gemm_k<0, 16><<<dim3(150, 1), 256, 0, stream>>>(xn, WqT, qbf, nullptr, nullptr, nullptr, nullptr, nullptr,
                                                    (int)MQ, CC, CC, QQ, NN);

    attn_k<<<64 * NSPLIT, 256, 0, stream>>>(qbf, kbf, vbf, Opb, lp);
    comb_k<<<(int)(MQ * 8 / 256), 256, 0, stream>>>(Opb, lp, aob);

    gemm_k<2, 16><<<dim3(150, 1), 256, 0, stream>>>(aob, WpT, nullptr, nullptr, pd, nullptr, nullptr, nullptr,
                                                    (int)MQ, CC, CC, (int)MQ, 0);
    ln2_k<<<(int)(MQ / 4), 256, 0, stream>>>(x, pd, g1, ln2w, ln2b, xqf, xqb);

    gemm_k<1, 16><<<dim3(150, 4), 256, 0, stream>>>(xqb, W1T, h1, nullptr, nullptr, nullptr, nullptr, nullptr,
                                                    (int)MQ, CC, HIDN, (int)MQ, 0);
    gemm_k<3, 16><<<dim3(150, 1), 256, 0, stream>>>(h1, W2T, nullptr, nullptr, nullptr, xqf, g2, out,
                                                    (int)MQ, HIDN, CC, (int)MQ, 0);
}